// Round 1
// baseline (409.791 us; speedup 1.0000x reference)
//
#include <hip/hip_runtime.h>
#include <hip/hip_bf16.h>

#define N 6144
#define EMB 256
#define HID 128
#define E_POS 98304
#define E_NEG 24576
#define E_POT 262144
#define E_TOT (E_POS + E_NEG + E_POT)   // 385024
#define SIGMA_INV (1.0f / 100.0f)
#define T_DEL 0.1f

__device__ __forceinline__ float sigm(float x) { return 1.0f / (1.0f + __expf(-x)); }

// ---------------------------------------------------------------------------
// MLP: latent = relu(emb @ W1 + b1) @ W2 + b2, for both branches (blockIdx.y).
// Block: 128 threads handle ROWS=16 rows. Thread = 2 cols x 8 rows register
// tile; emb rows staged in LDS, read as single-address float4 broadcasts
// (conflict-free). Also zeroes the loss accumulators (runs before edge_kernel
// in stream order).
// ---------------------------------------------------------------------------
#define ROWS 16
#define EPITCH 260   // 256 + 4: multiple of 4 for float4, breaks bank stride
#define HPITCH 132   // 128 + 4

__global__ __launch_bounds__(128)
void mlp_kernel(const float* __restrict__ emb,
                const float* __restrict__ Wl1, const float* __restrict__ bl1,
                const float* __restrict__ Wl2, const float* __restrict__ bl2,
                const float* __restrict__ Wa1, const float* __restrict__ ba1,
                const float* __restrict__ Wa2, const float* __restrict__ ba2,
                float* __restrict__ latL, float* __restrict__ latA,
                float* __restrict__ ws_acc)
{
    const int t = threadIdx.x;
    const int branch = blockIdx.y;
    const float* W1 = branch ? Wa1 : Wl1;
    const float* b1 = branch ? ba1 : bl1;
    const float* W2 = branch ? Wa2 : Wl2;
    const float* b2 = branch ? ba2 : bl2;
    float* lat = branch ? latA : latL;

    if (blockIdx.x == 0 && branch == 0 && t == 0) { ws_acc[0] = 0.f; ws_acc[1] = 0.f; }

    __shared__ float embS[ROWS * EPITCH];
    __shared__ float hidS[ROWS * HPITCH];

    const int row0 = blockIdx.x * ROWS;

    // stage emb rows: 16 rows x 64 float4 = 1024 float4, 128 threads -> 8 iters
    for (int idx = t; idx < ROWS * (EMB / 4); idx += 128) {
        int r = idx >> 6;
        int c4 = (idx & 63) << 2;
        *(float4*)(embS + r * EPITCH + c4) =
            *(const float4*)(emb + (size_t)(row0 + r) * EMB + c4);
    }
    __syncthreads();

    const int h0 = (t & 63) * 2;   // 2 output cols
    const int rb = (t >> 6) * 8;   // 8 rows (wave0: rows 0-7, wave1: rows 8-15)

    float accx[8], accy[8];

    // ---- layer 1: hidden = relu(emb @ W1 + b1) ----
    {
        float2 bb = *(const float2*)(b1 + h0);
        #pragma unroll
        for (int i = 0; i < 8; i++) { accx[i] = bb.x; accy[i] = bb.y; }
        for (int k = 0; k < EMB; k += 4) {
            float2 w0 = *(const float2*)(W1 + (size_t)(k + 0) * HID + h0);
            float2 w1 = *(const float2*)(W1 + (size_t)(k + 1) * HID + h0);
            float2 w2 = *(const float2*)(W1 + (size_t)(k + 2) * HID + h0);
            float2 w3 = *(const float2*)(W1 + (size_t)(k + 3) * HID + h0);
            #pragma unroll
            for (int i = 0; i < 8; i++) {
                float4 e = *(const float4*)(embS + (rb + i) * EPITCH + k);
                accx[i] += e.x * w0.x + e.y * w1.x + e.z * w2.x + e.w * w3.x;
                accy[i] += e.x * w0.y + e.y * w1.y + e.z * w2.y + e.w * w3.y;
            }
        }
        #pragma unroll
        for (int i = 0; i < 8; i++) {
            *(float2*)(hidS + (rb + i) * HPITCH + h0) =
                make_float2(fmaxf(accx[i], 0.f), fmaxf(accy[i], 0.f));
        }
    }
    __syncthreads();

    // ---- layer 2: latent = hidden @ W2 + b2 ----
    {
        float2 bb = *(const float2*)(b2 + h0);
        #pragma unroll
        for (int i = 0; i < 8; i++) { accx[i] = bb.x; accy[i] = bb.y; }
        for (int k = 0; k < HID; k += 4) {
            float2 w0 = *(const float2*)(W2 + (size_t)(k + 0) * HID + h0);
            float2 w1 = *(const float2*)(W2 + (size_t)(k + 1) * HID + h0);
            float2 w2 = *(const float2*)(W2 + (size_t)(k + 2) * HID + h0);
            float2 w3 = *(const float2*)(W2 + (size_t)(k + 3) * HID + h0);
            #pragma unroll
            for (int i = 0; i < 8; i++) {
                float4 e = *(const float4*)(hidS + (rb + i) * HPITCH + k);
                accx[i] += e.x * w0.x + e.y * w1.x + e.z * w2.x + e.w * w3.x;
                accy[i] += e.x * w0.y + e.y * w1.y + e.z * w2.y + e.w * w3.y;
            }
        }
        #pragma unroll
        for (int i = 0; i < 8; i++) {
            *(float2*)(lat + (size_t)(row0 + rb + i) * HID + h0) =
                make_float2(accx[i], accy[i]);
        }
    }
}

// ---------------------------------------------------------------------------
// Edge kernel: quarter-wave (16 lanes) per edge, 4 edges per wave, persistent
// grid-stride. Each lane loads 8 contiguous floats (2x float4, coalesced
// 256B segments) of each of the 4 latent rows, partial-dots, 4-level xor
// reduce within the 16-lane group. Subgroup leader does the sigmoid tail:
// poten -> write pw; pos/neg -> accumulate weighted loss in registers.
// Per-wave + per-block reduction -> 2 atomics per block.
// ---------------------------------------------------------------------------
__global__ __launch_bounds__(256)
void edge_kernel(const float* __restrict__ latL, const float* __restrict__ latA,
                 const float* __restrict__ aa, const float* __restrict__ fd,
                 const int* __restrict__ ei, const int* __restrict__ ne,
                 const int* __restrict__ pe,
                 const float* __restrict__ ewp, const float* __restrict__ swp,
                 float* __restrict__ out, float* __restrict__ ws_acc)
{
    const int t = threadIdx.x;
    const int lane = t & 63;
    const int s = lane & 15;      // lane within subgroup
    const int q = lane >> 4;      // subgroup (edge slot) within wave
    const int wslot = t >> 6;
    const int wid = (blockIdx.x * blockDim.x + t) >> 6;
    const int nwav = (gridDim.x * blockDim.x) >> 6;
    const float ew = ewp[0];
    const float sw = swp[0];

    float posAcc = 0.f, negAcc = 0.f;

    const int ngroups = E_TOT / 4;  // 96256, wave handles 4 edges per group
    for (int g = wid; g < ngroups; g += nwav) {
        const int e = g * 4 + q;
        int i, j, cls, qq = 0;
        if (e < E_POS)                { cls = 0; i = ei[e];            j = ei[E_POS + e]; }
        else if (e < E_POS + E_NEG)   { cls = 1; int u = e - E_POS;    i = ne[u]; j = ne[E_NEG + u]; }
        else                          { cls = 2; qq = e - (E_POS + E_NEG); i = pe[qq]; j = pe[E_POT + qq]; }

        const float* Li = latL + (size_t)i * HID;
        const float* Lj = latL + (size_t)j * HID;
        const float* Ai = latA + (size_t)i * HID;
        const float* Aj = latA + (size_t)j * HID;
        const int k1 = s * 4, k2 = 64 + s * 4;

        float4 a1 = *(const float4*)(Li + k1), a2 = *(const float4*)(Li + k2);
        float4 b1 = *(const float4*)(Lj + k1), b2 = *(const float4*)(Lj + k2);
        float4 c1 = *(const float4*)(Ai + k1), c2 = *(const float4*)(Ai + k2);
        float4 d1 = *(const float4*)(Aj + k1), d2 = *(const float4*)(Aj + k2);

        float dl = a1.x * b1.x + a1.y * b1.y + a1.z * b1.z + a1.w * b1.w
                 + a2.x * b2.x + a2.y * b2.y + a2.z * b2.z + a2.w * b2.w;
        float da = c1.x * d1.x + c1.y * d1.y + c1.z * d1.z + c1.w * d1.w
                 + c2.x * d2.x + c2.y * d2.y + c2.z * d2.z + c2.w * d2.w;

        #pragma unroll
        for (int off = 8; off >= 1; off >>= 1) {
            dl += __shfl_xor(dl, off, 64);
            da += __shfl_xor(da, off, 64);
        }

        if (s == 0) {
            const size_t o2 = (size_t)i * N + j;
            const float av = aa[o2];
            const float lc = sigm(dl);
            const float ac = sigm(da * av);
            const float p = sigm(ew * lc + sw * ac);
            if (cls == 2) {
                out[1 + qq] = (p < T_DEL) ? 0.f : p;
            } else {
                const float f = fd[o2] * SIGMA_INV;
                const float f2 = f * f;
                if (cls == 0) { const float w = __expf(-f2); const float d = p - 1.f; posAcc += w * d * d; }
                else          { const float w = __expf(f2);  negAcc += w * p * p; }
            }
        }
    }

    // wave reduce (only s==0 lanes hold nonzero)
    #pragma unroll
    for (int off = 32; off >= 1; off >>= 1) {
        posAcc += __shfl_xor(posAcc, off, 64);
        negAcc += __shfl_xor(negAcc, off, 64);
    }
    __shared__ float red[4][2];
    if (lane == 0) { red[wslot][0] = posAcc; red[wslot][1] = negAcc; }
    __syncthreads();
    if (t == 0) {
        float p = 0.f, n2 = 0.f;
        #pragma unroll
        for (int w = 0; w < 4; w++) { p += red[w][0]; n2 += red[w][1]; }
        atomicAdd(&ws_acc[0], p);
        atomicAdd(&ws_acc[1], n2);
    }
}

__global__ void finalize_kernel(const float* __restrict__ ws_acc, float* __restrict__ out)
{
    if (threadIdx.x == 0)
        out[0] = (ws_acc[0] + ws_acc[1]) * ((float)N / (float)(E_POS + E_NEG));
}

extern "C" void kernel_launch(void* const* d_in, const int* in_sizes, int n_in,
                              void* d_out, int out_size, void* d_ws, size_t ws_size,
                              hipStream_t stream)
{
    const float* emb = (const float*)d_in[0];
    const float* aa  = (const float*)d_in[1];
    const float* fd  = (const float*)d_in[2];
    const float* Wl1 = (const float*)d_in[3];
    const float* bl1 = (const float*)d_in[4];
    const float* Wl2 = (const float*)d_in[5];
    const float* bl2 = (const float*)d_in[6];
    const float* Wa1 = (const float*)d_in[7];
    const float* ba1 = (const float*)d_in[8];
    const float* Wa2 = (const float*)d_in[9];
    const float* ba2 = (const float*)d_in[10];
    const float* ewp = (const float*)d_in[11];
    const float* swp = (const float*)d_in[12];
    const int* ei = (const int*)d_in[13];
    const int* ne = (const int*)d_in[14];
    const int* pe = (const int*)d_in[15];

    float* out = (float*)d_out;
    float* ws  = (float*)d_ws;
    // ws layout: [0..1] loss accumulators (zeroed by mlp_kernel), 256B pad,
    // then latL [N*HID] and latA [N*HID] fp32 (~6.3 MB total)
    float* latL = ws + 64;
    float* latA = latL + (size_t)N * HID;

    mlp_kernel<<<dim3(N / ROWS, 2), 128, 0, stream>>>(
        emb, Wl1, bl1, Wl2, bl2, Wa1, ba1, Wa2, ba2, latL, latA, ws);

    edge_kernel<<<1024, 256, 0, stream>>>(
        latL, latA, aa, fd, ei, ne, pe, ewp, swp, out, ws);

    finalize_kernel<<<1, 64, 0, stream>>>(ws, out);
}

// Round 2
// 407.699 us; speedup vs baseline: 1.0051x; 1.0051x over previous
//
#include <hip/hip_runtime.h>
#include <hip/hip_bf16.h>

#define N 6144
#define EMB 256
#define HID 128
#define E_POS 98304
#define E_NEG 24576
#define E_POT 262144
#define E_TOT (E_POS + E_NEG + E_POT)   // 385024
#define SIGMA_INV (1.0f / 100.0f)
#define T_DEL 0.1f

__device__ __forceinline__ float sigm(float x) { return 1.0f / (1.0f + __expf(-x)); }

// round-to-nearest-even fp32 -> bf16 (values are finite/normal here)
__device__ __forceinline__ unsigned short f2bf(float f) {
    unsigned u = __float_as_uint(f);
    u += 0x7fffu + ((u >> 16) & 1u);
    return (unsigned short)(u >> 16);
}

// dot of 8 bf16 pairs packed in uint4 (2 bf16 per uint), accumulated in fp32
__device__ __forceinline__ float dot8(uint4 a, uint4 b) {
    float s;
    s  = __uint_as_float(a.x << 16)        * __uint_as_float(b.x << 16);
    s += __uint_as_float(a.x & 0xffff0000u) * __uint_as_float(b.x & 0xffff0000u);
    s += __uint_as_float(a.y << 16)        * __uint_as_float(b.y << 16);
    s += __uint_as_float(a.y & 0xffff0000u) * __uint_as_float(b.y & 0xffff0000u);
    s += __uint_as_float(a.z << 16)        * __uint_as_float(b.z << 16);
    s += __uint_as_float(a.z & 0xffff0000u) * __uint_as_float(b.z & 0xffff0000u);
    s += __uint_as_float(a.w << 16)        * __uint_as_float(b.w << 16);
    s += __uint_as_float(a.w & 0xffff0000u) * __uint_as_float(b.w & 0xffff0000u);
    return s;
}

// ---------------------------------------------------------------------------
// MLP: latent = relu(emb @ W1 + b1) @ W2 + b2, both branches (blockIdx.y).
// 128 threads / 16 rows; thread = 2 cols x 8 rows; emb staged in LDS.
// Latents stored as bf16 (so both fit one XCD's 4 MiB L2 in edge_kernel).
// Also zeroes the loss accumulators (stream-ordered before edge_kernel).
// ---------------------------------------------------------------------------
#define ROWS 16
#define EPITCH 260
#define HPITCH 132

__global__ __launch_bounds__(128)
void mlp_kernel(const float* __restrict__ emb,
                const float* __restrict__ Wl1, const float* __restrict__ bl1,
                const float* __restrict__ Wl2, const float* __restrict__ bl2,
                const float* __restrict__ Wa1, const float* __restrict__ ba1,
                const float* __restrict__ Wa2, const float* __restrict__ ba2,
                unsigned short* __restrict__ latL, unsigned short* __restrict__ latA,
                float* __restrict__ ws_acc)
{
    const int t = threadIdx.x;
    const int branch = blockIdx.y;
    const float* W1 = branch ? Wa1 : Wl1;
    const float* b1 = branch ? ba1 : bl1;
    const float* W2 = branch ? Wa2 : Wl2;
    const float* b2 = branch ? ba2 : bl2;
    unsigned short* lat = branch ? latA : latL;

    if (blockIdx.x == 0 && branch == 0 && t == 0) { ws_acc[0] = 0.f; ws_acc[1] = 0.f; }

    __shared__ float embS[ROWS * EPITCH];
    __shared__ float hidS[ROWS * HPITCH];

    const int row0 = blockIdx.x * ROWS;

    for (int idx = t; idx < ROWS * (EMB / 4); idx += 128) {
        int r = idx >> 6;
        int c4 = (idx & 63) << 2;
        *(float4*)(embS + r * EPITCH + c4) =
            *(const float4*)(emb + (size_t)(row0 + r) * EMB + c4);
    }
    __syncthreads();

    const int h0 = (t & 63) * 2;
    const int rb = (t >> 6) * 8;

    float accx[8], accy[8];

    // layer 1
    {
        float2 bb = *(const float2*)(b1 + h0);
        #pragma unroll
        for (int i = 0; i < 8; i++) { accx[i] = bb.x; accy[i] = bb.y; }
        for (int k = 0; k < EMB; k += 4) {
            float2 w0 = *(const float2*)(W1 + (size_t)(k + 0) * HID + h0);
            float2 w1 = *(const float2*)(W1 + (size_t)(k + 1) * HID + h0);
            float2 w2 = *(const float2*)(W1 + (size_t)(k + 2) * HID + h0);
            float2 w3 = *(const float2*)(W1 + (size_t)(k + 3) * HID + h0);
            #pragma unroll
            for (int i = 0; i < 8; i++) {
                float4 e = *(const float4*)(embS + (rb + i) * EPITCH + k);
                accx[i] += e.x * w0.x + e.y * w1.x + e.z * w2.x + e.w * w3.x;
                accy[i] += e.x * w0.y + e.y * w1.y + e.z * w2.y + e.w * w3.y;
            }
        }
        #pragma unroll
        for (int i = 0; i < 8; i++) {
            *(float2*)(hidS + (rb + i) * HPITCH + h0) =
                make_float2(fmaxf(accx[i], 0.f), fmaxf(accy[i], 0.f));
        }
    }
    __syncthreads();

    // layer 2
    {
        float2 bb = *(const float2*)(b2 + h0);
        #pragma unroll
        for (int i = 0; i < 8; i++) { accx[i] = bb.x; accy[i] = bb.y; }
        for (int k = 0; k < HID; k += 4) {
            float2 w0 = *(const float2*)(W2 + (size_t)(k + 0) * HID + h0);
            float2 w1 = *(const float2*)(W2 + (size_t)(k + 1) * HID + h0);
            float2 w2 = *(const float2*)(W2 + (size_t)(k + 2) * HID + h0);
            float2 w3 = *(const float2*)(W2 + (size_t)(k + 3) * HID + h0);
            #pragma unroll
            for (int i = 0; i < 8; i++) {
                float4 e = *(const float4*)(hidS + (rb + i) * HPITCH + k);
                accx[i] += e.x * w0.x + e.y * w1.x + e.z * w2.x + e.w * w3.x;
                accy[i] += e.x * w0.y + e.y * w1.y + e.z * w2.y + e.w * w3.y;
            }
        }
        #pragma unroll
        for (int i = 0; i < 8; i++) {
            unsigned short bx = f2bf(accx[i]);
            unsigned short by = f2bf(accy[i]);
            *(ushort2*)(lat + (size_t)(row0 + rb + i) * HID + h0) = make_ushort2(bx, by);
        }
    }
}

// ---------------------------------------------------------------------------
// Edge kernel (bf16 latents): 16 lanes per edge, 4 edges/wave. Lane s loads
// one uint4 (8 bf16) of each of the 4 rows -> coalesced 256 B row segments,
// L2-resident (3.1 MB total latents < 4 MiB/XCD). aa/fd gathers issued by
// the leader BEFORE the dot chain so their ~900-cyc HBM latency overlaps.
// ---------------------------------------------------------------------------
__global__ __launch_bounds__(256)
void edge_kernel(const unsigned short* __restrict__ latL,
                 const unsigned short* __restrict__ latA,
                 const float* __restrict__ aa, const float* __restrict__ fd,
                 const int* __restrict__ ei, const int* __restrict__ ne,
                 const int* __restrict__ pe,
                 const float* __restrict__ ewp, const float* __restrict__ swp,
                 float* __restrict__ out, float* __restrict__ ws_acc)
{
    const int t = threadIdx.x;
    const int lane = t & 63;
    const int s = lane & 15;
    const int q = lane >> 4;
    const int wslot = t >> 6;
    const int wid = (blockIdx.x * blockDim.x + t) >> 6;
    const int nwav = (gridDim.x * blockDim.x) >> 6;
    const float ew = ewp[0];
    const float sw = swp[0];

    float posAcc = 0.f, negAcc = 0.f;

    const int ngroups = E_TOT / 4;
    for (int g = wid; g < ngroups; g += nwav) {
        const int e = g * 4 + q;
        int i, j, cls, qq = 0;
        if (e < E_POS)                { cls = 0; i = ei[e];            j = ei[E_POS + e]; }
        else if (e < E_POS + E_NEG)   { cls = 1; int u = e - E_POS;    i = ne[u]; j = ne[E_NEG + u]; }
        else                          { cls = 2; qq = e - (E_POS + E_NEG); i = pe[qq]; j = pe[E_POT + qq]; }

        const size_t o2 = (size_t)i * N + j;
        // early gather issue: overlap random-access latency with the dots
        float av = 0.f, fv = 0.f;
        if (s == 0) {
            av = aa[o2];
            if (cls < 2) fv = fd[o2];
        }

        uint4 a = ((const uint4*)(latL + (size_t)i * HID))[s];
        uint4 b = ((const uint4*)(latL + (size_t)j * HID))[s];
        uint4 c = ((const uint4*)(latA + (size_t)i * HID))[s];
        uint4 d = ((const uint4*)(latA + (size_t)j * HID))[s];

        float dl = dot8(a, b);
        float da = dot8(c, d);

        #pragma unroll
        for (int off = 8; off >= 1; off >>= 1) {
            dl += __shfl_xor(dl, off, 64);
            da += __shfl_xor(da, off, 64);
        }

        if (s == 0) {
            const float lc = sigm(dl);
            const float ac = sigm(da * av);
            const float p = sigm(ew * lc + sw * ac);
            if (cls == 2) {
                out[1 + qq] = (p < T_DEL) ? 0.f : p;
            } else {
                const float f = fv * SIGMA_INV;
                const float f2 = f * f;
                if (cls == 0) { const float w = __expf(-f2); const float dd = p - 1.f; posAcc += w * dd * dd; }
                else          { const float w = __expf(f2);  negAcc += w * p * p; }
            }
        }
    }

    #pragma unroll
    for (int off = 32; off >= 1; off >>= 1) {
        posAcc += __shfl_xor(posAcc, off, 64);
        negAcc += __shfl_xor(negAcc, off, 64);
    }
    __shared__ float red[4][2];
    if (lane == 0) { red[wslot][0] = posAcc; red[wslot][1] = negAcc; }
    __syncthreads();
    if (t == 0) {
        float p = 0.f, n2 = 0.f;
        #pragma unroll
        for (int w = 0; w < 4; w++) { p += red[w][0]; n2 += red[w][1]; }
        atomicAdd(&ws_acc[0], p);
        atomicAdd(&ws_acc[1], n2);
    }
}

__global__ void finalize_kernel(const float* __restrict__ ws_acc, float* __restrict__ out)
{
    if (threadIdx.x == 0)
        out[0] = (ws_acc[0] + ws_acc[1]) * ((float)N / (float)(E_POS + E_NEG));
}

extern "C" void kernel_launch(void* const* d_in, const int* in_sizes, int n_in,
                              void* d_out, int out_size, void* d_ws, size_t ws_size,
                              hipStream_t stream)
{
    const float* emb = (const float*)d_in[0];
    const float* aa  = (const float*)d_in[1];
    const float* fd  = (const float*)d_in[2];
    const float* Wl1 = (const float*)d_in[3];
    const float* bl1 = (const float*)d_in[4];
    const float* Wl2 = (const float*)d_in[5];
    const float* bl2 = (const float*)d_in[6];
    const float* Wa1 = (const float*)d_in[7];
    const float* ba1 = (const float*)d_in[8];
    const float* Wa2 = (const float*)d_in[9];
    const float* ba2 = (const float*)d_in[10];
    const float* ewp = (const float*)d_in[11];
    const float* swp = (const float*)d_in[12];
    const int* ei = (const int*)d_in[13];
    const int* ne = (const int*)d_in[14];
    const int* pe = (const int*)d_in[15];

    float* out = (float*)d_out;
    float* ws  = (float*)d_ws;
    // ws layout: [0..1] loss accumulators (zeroed by mlp_kernel), pad to 256B,
    // then latL [N*HID] bf16 and latA [N*HID] bf16 (~3.1 MB total)
    unsigned short* latL = (unsigned short*)(ws + 64);
    unsigned short* latA = latL + (size_t)N * HID;

    mlp_kernel<<<dim3(N / ROWS, 2), 128, 0, stream>>>(
        emb, Wl1, bl1, Wl2, bl2, Wa1, ba1, Wa2, ba2, latL, latA, ws);

    edge_kernel<<<2048, 256, 0, stream>>>(
        latL, latA, aa, fd, ei, ne, pe, ewp, swp, out, ws);

    finalize_kernel<<<1, 64, 0, stream>>>(ws, out);
}